// Round 1
// baseline (182.429 us; speedup 1.0000x reference)
//
#include <hip/hip_runtime.h>

#define N_POINTS 65536
#define DIM 256
#define KNB 16
#define PAIR_BLOCKS 2048

// -------- Kernel 1: reciprocal L2 norms, one wave (64 lanes) per row --------
__global__ void rnorm_kernel(const float* __restrict__ feat, float* __restrict__ rnorm) {
    const int gwave = (blockIdx.x * blockDim.x + threadIdx.x) >> 6;
    const int lane = threadIdx.x & 63;
    if (gwave >= N_POINTS) return;
    const float4 v = reinterpret_cast<const float4*>(feat + (size_t)gwave * DIM)[lane];
    float s = v.x * v.x + v.y * v.y + v.z * v.z + v.w * v.w;
    #pragma unroll
    for (int off = 32; off; off >>= 1) s += __shfl_xor(s, off, 64);
    if (lane == 0) rnorm[gwave] = 1.0f / fmaxf(sqrtf(s), 1e-12f);
}

// -------- Kernel 2: per-point neighbor dots + masked partial reductions ----
// One wave per point; all 64 lanes hold 4 contiguous floats of row i (float4).
// Per-block partials (pos_sum, neg_sum, pos_cnt, neg_cnt) -> atomic-free.
__global__ void pair_kernel(const float* __restrict__ feat,
                            const float* __restrict__ rnorm,
                            const int* __restrict__ labels,
                            const int* __restrict__ idx,
                            float* __restrict__ partial /* [gridDim.x*4] */) {
    const int lane = threadIdx.x & 63;
    const int wib = threadIdx.x >> 6;                 // wave in block
    const int wavesPerBlock = blockDim.x >> 6;
    const int gwave = blockIdx.x * wavesPerBlock + wib;
    const int nwaves = gridDim.x * wavesPerBlock;

    float pos_sum = 0.f, neg_sum = 0.f, pos_cnt = 0.f, neg_cnt = 0.f;

    for (int p = gwave; p < N_POINTS; p += nwaves) {
        const int li = labels[p];
        const float rni = rnorm[p];
        const float4 fi = reinterpret_cast<const float4*>(feat + (size_t)p * DIM)[lane];
        #pragma unroll
        for (int k = 0; k < KNB; ++k) {
            const int j = idx[p * KNB + k];           // wave-uniform
            if (j < 0) continue;                      // knn_mask (uniform branch)
            const int lj = labels[j];
            const float4 fj = reinterpret_cast<const float4*>(feat + (size_t)j * DIM)[lane];
            float d = fi.x * fj.x + fi.y * fj.y + fi.z * fj.z + fi.w * fj.w;
            #pragma unroll
            for (int off = 32; off; off >>= 1) d += __shfl_xor(d, off, 64);
            const float cosv = d * rni * rnorm[j];    // same value in all lanes
            const bool valid = (li != -1) && (lj != -1);
            if (valid && (li == lj)) {                // positive pair
                pos_sum += 1.0f - cosv;
                pos_cnt += 1.0f;
            } else if (valid) {                       // negative pair
                neg_sum += fmaxf(cosv - 0.5f, 0.0f);
                neg_cnt += 1.0f;
            }
        }
    }

    // block combine: lane 0 of each wave -> LDS, thread 0 writes partials
    __shared__ float s_acc[4][4];                     // [wave][component]
    if (lane == 0) {
        s_acc[wib][0] = pos_sum;
        s_acc[wib][1] = neg_sum;
        s_acc[wib][2] = pos_cnt;
        s_acc[wib][3] = neg_cnt;
    }
    __syncthreads();
    if (threadIdx.x == 0) {
        float a0 = 0.f, a1 = 0.f, a2 = 0.f, a3 = 0.f;
        for (int w = 0; w < wavesPerBlock; ++w) {
            a0 += s_acc[w][0]; a1 += s_acc[w][1]; a2 += s_acc[w][2]; a3 += s_acc[w][3];
        }
        float* out = partial + (size_t)blockIdx.x * 4;
        out[0] = a0; out[1] = a1; out[2] = a2; out[3] = a3;
    }
}

// -------- Kernel 3: reduce partials, compute final scalar loss -------------
__global__ void finalize_kernel(const float* __restrict__ partial, int nblocks,
                                float* __restrict__ out) {
    float v0 = 0.f, v1 = 0.f, v2 = 0.f, v3 = 0.f;
    for (int i = threadIdx.x; i < nblocks; i += blockDim.x) {
        const float* p = partial + (size_t)i * 4;
        v0 += p[0]; v1 += p[1]; v2 += p[2]; v3 += p[3];
    }
    #pragma unroll
    for (int off = 32; off; off >>= 1) {
        v0 += __shfl_xor(v0, off, 64);
        v1 += __shfl_xor(v1, off, 64);
        v2 += __shfl_xor(v2, off, 64);
        v3 += __shfl_xor(v3, off, 64);
    }
    __shared__ float s[4][4];
    const int wave = threadIdx.x >> 6, lane = threadIdx.x & 63;
    if (lane == 0) { s[wave][0] = v0; s[wave][1] = v1; s[wave][2] = v2; s[wave][3] = v3; }
    __syncthreads();
    if (threadIdx.x == 0) {
        float ps = 0.f, ns = 0.f, pc = 0.f, nc = 0.f;
        for (int w = 0; w < 4; ++w) { ps += s[w][0]; ns += s[w][1]; pc += s[w][2]; nc += s[w][3]; }
        const float pos_loss = ps / fmaxf(pc, 1.0f);
        const float neg_loss = (nc > 0.f) ? (ns / fmaxf(nc, 1.0f)) : 0.f;
        out[0] = pos_loss + 0.5f * neg_loss;
    }
}

extern "C" void kernel_launch(void* const* d_in, const int* in_sizes, int n_in,
                              void* d_out, int out_size, void* d_ws, size_t ws_size,
                              hipStream_t stream) {
    const float* feat  = (const float*)d_in[0];
    const int* labels  = (const int*)d_in[1];
    const int* idx     = (const int*)d_in[2];
    float* out         = (float*)d_out;

    float* rnorm   = (float*)d_ws;                       // N floats (256 KB)
    float* partial = (float*)d_ws + N_POINTS;            // PAIR_BLOCKS*4 floats (32 KB)

    // 1) reciprocal norms: 4 waves/block -> N/4 blocks
    rnorm_kernel<<<N_POINTS / 4, 256, 0, stream>>>(feat, rnorm);

    // 2) pairwise dots + masked partial sums
    pair_kernel<<<PAIR_BLOCKS, 256, 0, stream>>>(feat, rnorm, labels, idx, partial);

    // 3) finalize scalar loss
    finalize_kernel<<<1, 256, 0, stream>>>(partial, PAIR_BLOCKS, out);
}

// Round 2
// 100.695 us; speedup vs baseline: 1.8117x; 1.8117x over previous
//
#include <hip/hip_runtime.h>
#include <hip/hip_fp16.h>

#define N_POINTS 65536
#define DIM 256
#define KNB 16
#define PAIR_BLOCKS 2048

// ============================ fp16 fast path ================================

// Kernel 1: normalize each row in fp32, store as fp16. One wave per row.
__global__ void norm_half_kernel(const float* __restrict__ feat,
                                 ushort* __restrict__ fh) {
    const int row = (blockIdx.x * blockDim.x + threadIdx.x) >> 6;
    const int lane = threadIdx.x & 63;
    const float4 v = reinterpret_cast<const float4*>(feat + (size_t)row * DIM)[lane];
    float s = v.x * v.x + v.y * v.y + v.z * v.z + v.w * v.w;
    #pragma unroll
    for (int off = 32; off; off >>= 1) s += __shfl_xor(s, off, 64);
    const float rn = 1.0f / fmaxf(sqrtf(s), 1e-12f);
    ushort4 o;
    o.x = __half_as_ushort(__float2half_rn(v.x * rn));
    o.y = __half_as_ushort(__float2half_rn(v.y * rn));
    o.z = __half_as_ushort(__float2half_rn(v.z * rn));
    o.w = __half_as_ushort(__float2half_rn(v.w * rn));
    reinterpret_cast<ushort4*>(fh + (size_t)row * DIM)[lane] = o;
}

__device__ __forceinline__ void unpack8(const uint4& w, float* f) {
    const __half2* h = reinterpret_cast<const __half2*>(&w);
    float2 a = __half22float2(h[0]); f[0] = a.x; f[1] = a.y;
    float2 b = __half22float2(h[1]); f[2] = b.x; f[3] = b.y;
    float2 c = __half22float2(h[2]); f[4] = c.x; f[5] = c.y;
    float2 e = __half22float2(h[3]); f[6] = e.x; f[7] = e.y;
}

// Kernel 2: one wave per point; 2 neighbors per iteration (one per half-wave).
// Row = 256 halves = 512 B = 32 lanes x 16 B.
__global__ void pair_kernel_h(const ushort* __restrict__ fh,
                              const int* __restrict__ labels,
                              const int* __restrict__ idx,
                              float* __restrict__ partial) {
    const int lane = threadIdx.x & 63;
    const int half = lane >> 5;            // which neighbor of the pair
    const int sub = lane & 31;
    const int wib = threadIdx.x >> 6;
    const int wavesPerBlock = blockDim.x >> 6;
    const int gwave = blockIdx.x * wavesPerBlock + wib;
    const int nwaves = gridDim.x * wavesPerBlock;

    float pos_sum = 0.f, neg_sum = 0.f, pos_cnt = 0.f, neg_cnt = 0.f;

    for (int p = gwave; p < N_POINTS; p += nwaves) {
        const int li = labels[p];
        const uint4 wi = reinterpret_cast<const uint4*>(fh + (size_t)p * DIM)[sub];
        float fi[8];
        unpack8(wi, fi);
        #pragma unroll
        for (int k0 = 0; k0 < KNB; k0 += 2) {
            const int j = idx[p * KNB + k0 + half];    // uniform per half-wave
            const int jc = (j < 0) ? 0 : j;
            const uint4 wj = reinterpret_cast<const uint4*>(fh + (size_t)jc * DIM)[sub];
            const int lj = labels[jc];
            float fj[8];
            unpack8(wj, fj);
            float d = fi[0] * fj[0];
            d = fmaf(fi[1], fj[1], d);
            d = fmaf(fi[2], fj[2], d);
            d = fmaf(fi[3], fj[3], d);
            d = fmaf(fi[4], fj[4], d);
            d = fmaf(fi[5], fj[5], d);
            d = fmaf(fi[6], fj[6], d);
            d = fmaf(fi[7], fj[7], d);
            #pragma unroll
            for (int off = 16; off; off >>= 1) d += __shfl_xor(d, off, 64);
            const bool valid = (j >= 0) && (li != -1) && (lj != -1);
            if (sub == 0 && valid) {
                if (li == lj) { pos_sum += 1.0f - d; pos_cnt += 1.0f; }
                else          { neg_sum += fmaxf(d - 0.5f, 0.0f); neg_cnt += 1.0f; }
            }
        }
    }

    // fold lane 32 into lane 0
    pos_sum += __shfl_xor(pos_sum, 32, 64);
    neg_sum += __shfl_xor(neg_sum, 32, 64);
    pos_cnt += __shfl_xor(pos_cnt, 32, 64);
    neg_cnt += __shfl_xor(neg_cnt, 32, 64);

    __shared__ float s_acc[4][4];
    if (lane == 0) {
        s_acc[wib][0] = pos_sum;
        s_acc[wib][1] = neg_sum;
        s_acc[wib][2] = pos_cnt;
        s_acc[wib][3] = neg_cnt;
    }
    __syncthreads();
    if (threadIdx.x == 0) {
        float a0 = 0.f, a1 = 0.f, a2 = 0.f, a3 = 0.f;
        for (int w = 0; w < wavesPerBlock; ++w) {
            a0 += s_acc[w][0]; a1 += s_acc[w][1]; a2 += s_acc[w][2]; a3 += s_acc[w][3];
        }
        float* out = partial + (size_t)blockIdx.x * 4;
        out[0] = a0; out[1] = a1; out[2] = a2; out[3] = a3;
    }
}

// ============================ fp32 fallback path ============================

__global__ void rnorm_kernel(const float* __restrict__ feat, float* __restrict__ rnorm) {
    const int gwave = (blockIdx.x * blockDim.x + threadIdx.x) >> 6;
    const int lane = threadIdx.x & 63;
    if (gwave >= N_POINTS) return;
    const float4 v = reinterpret_cast<const float4*>(feat + (size_t)gwave * DIM)[lane];
    float s = v.x * v.x + v.y * v.y + v.z * v.z + v.w * v.w;
    #pragma unroll
    for (int off = 32; off; off >>= 1) s += __shfl_xor(s, off, 64);
    if (lane == 0) rnorm[gwave] = 1.0f / fmaxf(sqrtf(s), 1e-12f);
}

__global__ void pair_kernel(const float* __restrict__ feat,
                            const float* __restrict__ rnorm,
                            const int* __restrict__ labels,
                            const int* __restrict__ idx,
                            float* __restrict__ partial) {
    const int lane = threadIdx.x & 63;
    const int wib = threadIdx.x >> 6;
    const int wavesPerBlock = blockDim.x >> 6;
    const int gwave = blockIdx.x * wavesPerBlock + wib;
    const int nwaves = gridDim.x * wavesPerBlock;

    float pos_sum = 0.f, neg_sum = 0.f, pos_cnt = 0.f, neg_cnt = 0.f;

    for (int p = gwave; p < N_POINTS; p += nwaves) {
        const int li = labels[p];
        const float rni = rnorm[p];
        const float4 fi = reinterpret_cast<const float4*>(feat + (size_t)p * DIM)[lane];
        #pragma unroll
        for (int k = 0; k < KNB; ++k) {
            const int j = idx[p * KNB + k];
            if (j < 0) continue;
            const int lj = labels[j];
            const float4 fj = reinterpret_cast<const float4*>(feat + (size_t)j * DIM)[lane];
            float d = fi.x * fj.x + fi.y * fj.y + fi.z * fj.z + fi.w * fj.w;
            #pragma unroll
            for (int off = 32; off; off >>= 1) d += __shfl_xor(d, off, 64);
            const float cosv = d * rni * rnorm[j];
            const bool valid = (li != -1) && (lj != -1);
            if (valid && (li == lj)) {
                pos_sum += 1.0f - cosv;
                pos_cnt += 1.0f;
            } else if (valid) {
                neg_sum += fmaxf(cosv - 0.5f, 0.0f);
                neg_cnt += 1.0f;
            }
        }
    }

    __shared__ float s_acc[4][4];
    if (lane == 0) {
        s_acc[wib][0] = pos_sum;
        s_acc[wib][1] = neg_sum;
        s_acc[wib][2] = pos_cnt;
        s_acc[wib][3] = neg_cnt;
    }
    __syncthreads();
    if (threadIdx.x == 0) {
        float a0 = 0.f, a1 = 0.f, a2 = 0.f, a3 = 0.f;
        for (int w = 0; w < wavesPerBlock; ++w) {
            a0 += s_acc[w][0]; a1 += s_acc[w][1]; a2 += s_acc[w][2]; a3 += s_acc[w][3];
        }
        float* out = partial + (size_t)blockIdx.x * 4;
        out[0] = a0; out[1] = a1; out[2] = a2; out[3] = a3;
    }
}

// ============================ finalize ======================================

__global__ void finalize_kernel(const float* __restrict__ partial, int nblocks,
                                float* __restrict__ out) {
    float v0 = 0.f, v1 = 0.f, v2 = 0.f, v3 = 0.f;
    for (int i = threadIdx.x; i < nblocks; i += blockDim.x) {
        const float* p = partial + (size_t)i * 4;
        v0 += p[0]; v1 += p[1]; v2 += p[2]; v3 += p[3];
    }
    #pragma unroll
    for (int off = 32; off; off >>= 1) {
        v0 += __shfl_xor(v0, off, 64);
        v1 += __shfl_xor(v1, off, 64);
        v2 += __shfl_xor(v2, off, 64);
        v3 += __shfl_xor(v3, off, 64);
    }
    __shared__ float s[4][4];
    const int wave = threadIdx.x >> 6, lane = threadIdx.x & 63;
    if (lane == 0) { s[wave][0] = v0; s[wave][1] = v1; s[wave][2] = v2; s[wave][3] = v3; }
    __syncthreads();
    if (threadIdx.x == 0) {
        float ps = 0.f, ns = 0.f, pc = 0.f, nc = 0.f;
        for (int w = 0; w < 4; ++w) { ps += s[w][0]; ns += s[w][1]; pc += s[w][2]; nc += s[w][3]; }
        const float pos_loss = ps / fmaxf(pc, 1.0f);
        const float neg_loss = (nc > 0.f) ? (ns / fmaxf(nc, 1.0f)) : 0.f;
        out[0] = pos_loss + 0.5f * neg_loss;
    }
}

// ============================ launch ========================================

extern "C" void kernel_launch(void* const* d_in, const int* in_sizes, int n_in,
                              void* d_out, int out_size, void* d_ws, size_t ws_size,
                              hipStream_t stream) {
    const float* feat  = (const float*)d_in[0];
    const int* labels  = (const int*)d_in[1];
    const int* idx     = (const int*)d_in[2];
    float* out         = (float*)d_out;

    const size_t half_bytes = (size_t)N_POINTS * DIM * sizeof(ushort);   // 32 MB
    const size_t part_bytes = (size_t)PAIR_BLOCKS * 4 * sizeof(float);   // 32 KB

    if (ws_size >= half_bytes + part_bytes) {
        // fp16 fast path
        ushort* fh     = (ushort*)d_ws;
        float* partial = (float*)((char*)d_ws + half_bytes);
        norm_half_kernel<<<N_POINTS / 4, 256, 0, stream>>>(feat, fh);
        pair_kernel_h<<<PAIR_BLOCKS, 256, 0, stream>>>(fh, labels, idx, partial);
        finalize_kernel<<<1, 256, 0, stream>>>(partial, PAIR_BLOCKS, out);
    } else {
        // fp32 fallback
        float* rnorm   = (float*)d_ws;
        float* partial = (float*)d_ws + N_POINTS;
        rnorm_kernel<<<N_POINTS / 4, 256, 0, stream>>>(feat, rnorm);
        pair_kernel<<<PAIR_BLOCKS, 256, 0, stream>>>(feat, rnorm, labels, idx, partial);
        finalize_kernel<<<1, 256, 0, stream>>>(partial, PAIR_BLOCKS, out);
    }
}